// Round 2
// baseline (395.390 us; speedup 1.0000x reference)
//
#include <hip/hip_runtime.h>

// Causal Toeplitz-conv GEMM. y[b,h,n] = sum_{m<=n} u[b,h,m]*K[h,n-m] + D[h]*u[b,h,n]
// Out complex64 interleaved (re,0). Block=(h, 16 tiles of 128), 4 waves (2x2),
// wave 64x64 via 4x4 x v_mfma_f32_16x16x32_bf16.
// A-operand (Toeplitz K) from global KR8 (8 shift copies):
// FULL distance-1 double-buffer — all 10 next-iter frags issued at the top of
// the current iteration (~1 full iteration of latency cover; the cold-cache
// timed run hits L3/HBM on KR8, where the old same-iteration af[6..9] loads
// had only ~100-300 cyc of cover -> per-iter stall, barrier-amplified).
// u staged f32 -> bf16 with DISTANCE-2 load prefetch; pack deferred to the
// post-compute commit point. Boundary col mask reduces to (m>>3)==0.
// LDS = sliding 17-slot u-window, row stride 136 shorts (conflict-minimal,
// measured 8.9e6 vs 6.1e7 at 128).

#define TILE 128
#define IGRP 16
#define SLOTS 17
#define BROW 136                        // shorts per (slot,b) row (128+8)
#define SLOT_STRIDE (8 * BROW)          // 1088 shorts
#define BS_SHORTS (SLOTS * SLOT_STRIDE) // 18496
#define KRC_STRIDE 264                  // tier0 LDS K row (shorts)
#define KRC_BUF (8 * KRC_STRIDE)        // 2112 shorts per buffer
#define EP_STRIDE 132

typedef short bf16x8 __attribute__((ext_vector_type(8)));
typedef float f32x4 __attribute__((ext_vector_type(4)));

__device__ __forceinline__ unsigned short f2bf(float f) {
    unsigned int u = __float_as_uint(f);
    u = (u + 0x7fffu + ((u >> 16) & 1u)) >> 16;  // RNE
    return (unsigned short)u;
}

// KR8[h][r][x] = bf16(K[h][L-1-(x-r)]) for x-r in [0,L), else 0.  r in 0..7.
// 2 elements per thread, dword stores.
__global__ void build_KR8(const float* __restrict__ K, unsigned short* __restrict__ KR8,
                          int L, int RS) {
    int x = (blockIdx.x * 256 + threadIdx.x) * 2;
    int r = blockIdx.y;
    long h = blockIdx.z;
    if (x + 1 >= RS + (RS & 1)) { }
    if (x >= RS) return;
    unsigned int w = 0;
    int t0 = x - r;
    if (t0 >= 0 && t0 < L) w = f2bf(K[h * L + (L - 1 - t0)]);
    int t1 = t0 + 1;
    if (x + 1 < RS && t1 >= 0 && t1 < L)
        w |= ((unsigned)f2bf(K[h * L + (L - 1 - t1)])) << 16;
    *(unsigned int*)(KR8 + (h * 8 + r) * (long)RS + x) = w;
}

template <int UK>
__global__ __launch_bounds__(256, 3) void conv_main(
    const float* __restrict__ u, const float* __restrict__ Kc,
    const float* __restrict__ Dp, const unsigned short* __restrict__ KR8,
    float* __restrict__ outf, int H, int L, int G, int RS, int cplx, long out_floats)
{
    __shared__ __align__(16) char smem[UK ? (BS_SHORTS * 2) : (BS_SHORTS * 2 + 2 * KRC_BUF * 2)];
    unsigned short* Bs = (unsigned short*)smem;
    unsigned short* Krc = (unsigned short*)(smem + BS_SHORTS * 2);  // tier0 only
    float* Ep = (float*)smem;

    const int tid  = threadIdx.x;
    const int lane = tid & 63;
    const int wv   = tid >> 6;
    const int wm   = wv >> 1;
    const int wn   = wv & 1;
    const int m    = lane & 15;
    const int quad = lane >> 4;
    const bool tb0 = (m < 8);           // lower-tile lanes (boundary mask)

    const int bx = blockIdx.x;
    const int h  = bx % H;
    const int g  = (G - 1) - (bx / H);  // big groups first
    const int i0 = g * IGRP;
    const int dmax = i0 + IGRP - 1;

    const int rA = (m + 1) & 7;
    const int t0b = 127 - wm * 64 - m + quad * 8;   // t0 base (rb=0,kc=0)
    const int cB = (m & 7) * BROW + quad * 8;       // shorts

    // A source pointer (UK=1): byte addr into KR8, slides -256 B per iter
    const char* pA = (const char*)(KR8 + ((long)(h * 8 + rA)) * RS)
                   + 2 * ((long)(L - TILE) + t0b + rA);
    // A source (UK=0): LDS Krc byte offset
    const int cAb = 2 * (rA * KRC_STRIDE + t0b + rA);

    // tier0 K-staging constants (5 chunks cover 1056 u32)
    int ldsK[5], taK[5];
    bool vK[5];
    if (UK == 0) {
        #pragma unroll
        for (int p = 0; p < 5; ++p) {
            int wi = tid + p * 256;
            vK[p] = wi < 1056;
            int rp = vK[p] ? (wi / 132) : 0;
            int tp = (wi - rp * 132) * 2;
            ldsK[p] = rp * KRC_STRIDE + tp;
            taK[p] = vK[p] ? (tp - rp) : -1000;
        }
    }
    const float* Kfrow = Kc + (long)h * L;

    // B staging: one (b-row, 4-float) chunk per thread
    const int bb = tid >> 5;
    const int q8 = (tid & 31) * 4;
    const long ubase = ((long)bb * H + h) * L;

    f32x4 acc[4][4];
    {
        f32x4 z = {0.f, 0.f, 0.f, 0.f};
        #pragma unroll
        for (int a = 0; a < 4; ++a)
            #pragma unroll
            for (int b = 0; b < 4; ++b) acc[a][b] = z;
    }

    int sc4[4];
    #pragma unroll
    for (int nb = 0; nb < 4; ++nb) {
        int il = wn * 8 + nb * 2 + (m >> 3);
        sc4[nb] = (i0 + il) % SLOTS;
    }
    int slotw = (i0 >= 1) ? ((i0 - 1) % SLOTS) : (SLOTS - 1);

    // ---- prologue: stage 16 window tiles (f32 -> bf16); tier0 also Krc[0] ----
    #pragma unroll
    for (int batch = 0; batch < 2; ++batch) {
        uint2 a8[8];
        #pragma unroll
        for (int q = 0; q < 8; ++q) {
            int j = i0 + batch * 8 + q;
            float4 v = *(const float4*)(u + ubase + (long)j * TILE + q8);
            a8[q].x = f2bf(v.x) | ((unsigned)f2bf(v.y) << 16);
            a8[q].y = f2bf(v.z) | ((unsigned)f2bf(v.w) << 16);
        }
        #pragma unroll
        for (int q = 0; q < 8; ++q) {
            int j = i0 + batch * 8 + q;
            *(uint2*)(Bs + (j % SLOTS) * SLOT_STRIDE + bb * BROW + q8) = a8[q];
        }
    }
    // distance-2 u prefetch: tile i0-1 (committed at iter 0)
    float4 fvA = {0.f, 0.f, 0.f, 0.f};
    if (i0 - 1 >= 0)
        fvA = *(const float4*)(u + ubase + (long)(i0 - 1) * TILE + q8);
    if (UK == 0) {
        #pragma unroll
        for (int p = 0; p < 5; ++p) {
            if (vK[p]) {
                unsigned int s0 = 0, s1 = 0;
                int ta = taK[p];
                int ka = 127 - ta;
                if (ta >= 0 && ta < 256 && ka >= 0) s0 = f2bf(Kfrow[ka]);
                if (ta + 1 >= 0 && ta + 1 < 256 && (ka - 1) >= 0) s1 = f2bf(Kfrow[ka - 1]);
                *(unsigned int*)(Krc + ldsK[p]) = s0 | (s1 << 16);
            }
        }
    }
    bf16x8 af[10], afn[10] = {};
    if (UK) {
        #pragma unroll
        for (int o = 0; o < 10; ++o) af[o] = *(const bf16x8*)(pA + (o - 3) * 32);
    }
    __syncthreads();

    const bf16x8 z8 = {};

    // ---- main loop: one barrier per iter ----
    for (int d = 0; d <= dmax; ++d) {
        const int dn = d + 1;
        const int jnA = i0 - 1 - d;   // tile committed this iter (loaded last iter)
        const int jnB = i0 - 2 - d;   // tile whose load is issued this iter

        // A frags: UK1 -> FULL next-iter prefetch issued first (one whole
        // iteration of latency cover; nothing A-related blocks this iter's
        // compute). UK0 -> all from LDS double buffer.
        if (UK) {
            if (d < dmax) {
                #pragma unroll
                for (int o = 0; o < 10; ++o) afn[o] = *(const bf16x8*)(pA - 256 + (o - 3) * 32);
            }
        } else {
            const char* Ab = (const char*)Krc + (d & 1) * (KRC_BUF * 2) + cAb;
            #pragma unroll
            for (int o = 0; o < 10; ++o) af[o] = *(const bf16x8*)(Ab + (o - 3) * 32);
        }

        // issue the distance-2 u load (consumed at iter d+1's commit point)
        float4 fvB = {0.f, 0.f, 0.f, 0.f};
        if (jnB >= 0)
            fvB = *(const float4*)(u + ubase + (long)jnB * TILE + q8);

        // tier0: K window values for next iter (guarded f32)
        unsigned int kv[5] = {0u, 0u, 0u, 0u, 0u};
        if (UK == 0 && dn <= dmax) {
            #pragma unroll
            for (int p = 0; p < 5; ++p) {
                unsigned int s0 = 0, s1 = 0;
                int ta = taK[p];
                if (vK[p]) {
                    int ka = dn * TILE + 127 - ta;
                    if (ta >= 0 && ta < 256 && ka >= 0) s0 = f2bf(Kfrow[ka]);
                    if (ta + 1 >= 0 && ta + 1 < 256 && (ka - 1) >= 0) s1 = f2bf(Kfrow[ka - 1]);
                }
                kv[p] = s0 | (s1 << 16);
            }
        }

        // ---- compute ----
        const int dlim = d - i0;
        const unsigned short* Bp[4];
        #pragma unroll
        for (int nb = 0; nb < 4; ++nb)
            Bp[nb] = Bs + sc4[nb] * SLOT_STRIDE + cB;

        #pragma unroll
        for (int kc = 0; kc < 4; ++kc) {
            #pragma unroll
            for (int nb = 0; nb < 4; ++nb) {
                const int nbg = wn * 4 + nb;
                if (2 * nbg + 1 >= dlim) {
                    bf16x8 bfr = *(const bf16x8*)(Bp[nb] + kc * 32);
                    // boundary col mask: col<0 at 2nbg+1==dlim  <=>  m>>3==0
                    if (2 * nbg + 1 == dlim) bfr = tb0 ? z8 : bfr;
                    acc[0][nb] = __builtin_amdgcn_mfma_f32_16x16x32_bf16(af[3 + 2 * kc], bfr, acc[0][nb], 0, 0, 0);
                    acc[1][nb] = __builtin_amdgcn_mfma_f32_16x16x32_bf16(af[2 + 2 * kc], bfr, acc[1][nb], 0, 0, 0);
                    acc[2][nb] = __builtin_amdgcn_mfma_f32_16x16x32_bf16(af[1 + 2 * kc], bfr, acc[2][nb], 0, 0, 0);
                    acc[3][nb] = __builtin_amdgcn_mfma_f32_16x16x32_bf16(af[0 + 2 * kc], bfr, acc[3][nb], 0, 0, 0);
                }
            }
        }

        // commit staged data for next iter (pack happens HERE, behind the MFMAs;
        // the f32 load landed a full iteration ago -> no vmcnt stall)
        if (UK == 0 && dn <= dmax) {
            unsigned short* Kw = Krc + (dn & 1) * KRC_BUF;
            #pragma unroll
            for (int p = 0; p < 5; ++p)
                if (vK[p]) *(unsigned int*)(Kw + ldsK[p]) = kv[p];
        }
        if (jnA >= 0) {
            uint2 bv;
            bv.x = f2bf(fvA.x) | ((unsigned)f2bf(fvA.y) << 16);
            bv.y = f2bf(fvA.z) | ((unsigned)f2bf(fvA.w) << 16);
            *(uint2*)(Bs + slotw * SLOT_STRIDE + bb * BROW + q8) = bv;
        }

        slotw = slotw ? slotw - 1 : SLOTS - 1;
        #pragma unroll
        for (int nb = 0; nb < 4; ++nb)
            sc4[nb] = sc4[nb] ? sc4[nb] - 1 : SLOTS - 1;
        if (UK) {
            #pragma unroll
            for (int o = 0; o < 10; ++o) af[o] = afn[o];
            pA -= 256;
        }
        fvA = fvB;
        __syncthreads();
    }

    // ---- epilogue: LDS transpose (2 passes), skip-add, store ----
    const float Dh = Dp[h];
    const int ec = tid >> 2;
    const int ps = (tid & 3) * 32;
    #pragma unroll
    for (int pass = 0; pass < 2; ++pass) {
        if (wn == pass) {
            #pragma unroll
            for (int rb = 0; rb < 4; ++rb) {
                int p = wm * 64 + rb * 16 + quad * 4;  // C/D row = quad*4+reg
                #pragma unroll
                for (int nb = 0; nb < 4; ++nb) {
                    int cloc = nb * 16 + m;            // C/D col = lane&15
                    *(f32x4*)(Ep + cloc * EP_STRIDE + p) = acc[rb][nb];
                }
            }
        }
        __syncthreads();
        {
            int cg = pass * 64 + ec;
            int b  = cg & 7;
            int i  = i0 + (cg >> 3);
            long base = ((long)b * H + h) * L + (long)i * TILE + ps;
            const float* ep = Ep + ec * EP_STRIDE + ps;
            const float* us = u + base;
            if (cplx) {
                if (2 * (base + 32) <= out_floats) {
                    float4* o = (float4*)(outf + 2 * base);
                    #pragma unroll
                    for (int k4 = 0; k4 < 8; ++k4) {
                        float4 uv = ((const float4*)us)[k4];
                        float4 ev = *(const float4*)(ep + k4 * 4);
                        float4 o1, o2;
                        o1.x = ev.x + Dh * uv.x; o1.y = 0.f;
                        o1.z = ev.y + Dh * uv.y; o1.w = 0.f;
                        o2.x = ev.z + Dh * uv.z; o2.y = 0.f;
                        o2.z = ev.w + Dh * uv.w; o2.w = 0.f;
                        o[k4 * 2]     = o1;
                        o[k4 * 2 + 1] = o2;
                    }
                }
            } else {
                if (base + 32 <= out_floats) {
                    float4* o = (float4*)(outf + base);
                    #pragma unroll
                    for (int k4 = 0; k4 < 8; ++k4) {
                        float4 uv = ((const float4*)us)[k4];
                        float4 ev = *(const float4*)(ep + k4 * 4);
                        float4 ov;
                        ov.x = ev.x + Dh * uv.x;
                        ov.y = ev.y + Dh * uv.y;
                        ov.z = ev.z + Dh * uv.z;
                        ov.w = ev.w + Dh * uv.w;
                        o[k4] = ov;
                    }
                }
            }
        }
        __syncthreads();
    }
}

extern "C" void kernel_launch(void* const* d_in, const int* in_sizes, int n_in,
                              void* d_out, int out_size, void* d_ws, size_t ws_size,
                              hipStream_t stream) {
    const float* u  = (const float*)d_in[0];
    const float* Kc = (const float*)d_in[1];
    const float* Dp = (const float*)d_in[2];
    const int H = in_sizes[2];
    const int L = in_sizes[1] / H;          // 8192
    const int G = L / (TILE * IGRP);        // 4
    const int RS = L + 272;
    const int cplx = (out_size >= 2 * in_sizes[0]) ? 1 : 0;

    const size_t kr8_bytes = (size_t)H * 8 * RS * 2;
    const int tier = (ws_size >= kr8_bytes) ? 1 : 0;
    unsigned short* KR8 = (unsigned short*)d_ws;

    if (tier) {
        dim3 gk((RS / 2 + 255) / 256, 8, H);
        build_KR8<<<gk, 256, 0, stream>>>(Kc, KR8, L, RS);
        conv_main<1><<<H * G, 256, 0, stream>>>(u, Kc, Dp, KR8, (float*)d_out,
                                                H, L, G, RS, cplx, (long)out_size);
    } else {
        conv_main<0><<<H * G, 256, 0, stream>>>(u, Kc, Dp, KR8, (float*)d_out,
                                                H, L, G, RS, cplx, (long)out_size);
    }
}

// Round 3
// 293.881 us; speedup vs baseline: 1.3454x; 1.3454x over previous
//
#include <hip/hip_runtime.h>

// Causal Toeplitz-conv GEMM. y[b,h,n] = sum_{m<=n} u[b,h,m]*K[h,n-m] + D[h]*u[b,h,n]
// Out complex64 interleaved (re,0). Block=(h, 16 tiles of 128), 4 waves (2x2),
// wave 64x64 via 4x4 x v_mfma_f32_16x16x32_bf16.
// A-operand (Toeplitz K) from global KR8 (8 shift copies, L1/L2-resident),
// half-register double-buffer (15 frags: fits 170-reg cap at (256,3)).
// SCHEDULE = R0 (proven latency-robust: cold == warm == ~210us). The u f32
// load is issued at iter top and consumed at the SAME iter's commit point
// (~full compute section of cover). Distance-2 prefetch REVERTED: a cold
// HBM u-miss ahead of the af loads in the VM FIFO head-of-line-blocks the
// kc=2/3 vmcnt waits (measured: cold 211 -> 303us in R1).
// Full A double-buffer REVERTED: +16 VGPR past the (256,3) cliff made the
// compiler spill/sink the prefetch (measured: warm 205 -> 306us in R2).
// Boundary col mask reduces to (m>>3)==0 (register-free, warm-verified).
// s_setprio(1) wraps the MFMA cluster (T5: 3 independent blocks/CU at
// different phases = role diversity for the CU scheduler).
// LDS = sliding 17-slot u-window, row stride 136 shorts (conflict-minimal,
// measured 8.9e6 vs 6.1e7 at 128).

#define TILE 128
#define IGRP 16
#define SLOTS 17
#define BROW 136                        // shorts per (slot,b) row (128+8)
#define SLOT_STRIDE (8 * BROW)          // 1088 shorts
#define BS_SHORTS (SLOTS * SLOT_STRIDE) // 18496
#define KRC_STRIDE 264                  // tier0 LDS K row (shorts)
#define KRC_BUF (8 * KRC_STRIDE)        // 2112 shorts per buffer
#define EP_STRIDE 132

typedef short bf16x8 __attribute__((ext_vector_type(8)));
typedef float f32x4 __attribute__((ext_vector_type(4)));

__device__ __forceinline__ unsigned short f2bf(float f) {
    unsigned int u = __float_as_uint(f);
    u = (u + 0x7fffu + ((u >> 16) & 1u)) >> 16;  // RNE
    return (unsigned short)u;
}

// KR8[h][r][x] = bf16(K[h][L-1-(x-r)]) for x-r in [0,L), else 0.  r in 0..7.
// 4 shorts per thread, 8B stores (4x fewer threads than scalar version).
__global__ __launch_bounds__(256) void build_KR8(
    const float* __restrict__ K, unsigned short* __restrict__ KR8, int L, int RS) {
    int x0 = (blockIdx.x * 256 + threadIdx.x) * 4;
    int r = blockIdx.y;
    long h = blockIdx.z;
    if (x0 >= RS) return;
    const float* Kh = K + h * (long)L;
    unsigned short s[4];
    #pragma unroll
    for (int j = 0; j < 4; ++j) {
        int t = x0 + j - r;
        s[j] = (t >= 0 && t < L) ? f2bf(Kh[L - 1 - t]) : (unsigned short)0;
    }
    uint2 w;
    w.x = s[0] | ((unsigned)s[1] << 16);
    w.y = s[2] | ((unsigned)s[3] << 16);
    *(uint2*)(KR8 + (h * 8 + r) * (long)RS + x0) = w;
}

template <int UK>
__global__ __launch_bounds__(256, 3) void conv_main(
    const float* __restrict__ u, const float* __restrict__ Kc,
    const float* __restrict__ Dp, const unsigned short* __restrict__ KR8,
    float* __restrict__ outf, int H, int L, int G, int RS, int cplx, long out_floats)
{
    __shared__ __align__(16) char smem[UK ? (BS_SHORTS * 2) : (BS_SHORTS * 2 + 2 * KRC_BUF * 2)];
    unsigned short* Bs = (unsigned short*)smem;
    unsigned short* Krc = (unsigned short*)(smem + BS_SHORTS * 2);  // tier0 only
    float* Ep = (float*)smem;

    const int tid  = threadIdx.x;
    const int lane = tid & 63;
    const int wv   = tid >> 6;
    const int wm   = wv >> 1;
    const int wn   = wv & 1;
    const int m    = lane & 15;
    const int quad = lane >> 4;
    const bool tb0 = (m < 8);           // lower-tile lanes (boundary mask)

    const int bx = blockIdx.x;
    const int h  = bx % H;
    const int g  = (G - 1) - (bx / H);  // big groups first
    const int i0 = g * IGRP;
    const int dmax = i0 + IGRP - 1;

    const int rA = (m + 1) & 7;
    const int t0b = 127 - wm * 64 - m + quad * 8;   // t0 base (rb=0,kc=0)
    const int cB = (m & 7) * BROW + quad * 8;       // shorts

    // A source pointer (UK=1): byte addr into KR8, slides -256 B per iter
    const char* pA = (const char*)(KR8 + ((long)(h * 8 + rA)) * RS)
                   + 2 * ((long)(L - TILE) + t0b + rA);
    // A source (UK=0): LDS Krc byte offset
    const int cAb = 2 * (rA * KRC_STRIDE + t0b + rA);

    // tier0 K-staging constants (5 chunks cover 1056 u32)
    int ldsK[5], taK[5];
    bool vK[5];
    if (UK == 0) {
        #pragma unroll
        for (int p = 0; p < 5; ++p) {
            int wi = tid + p * 256;
            vK[p] = wi < 1056;
            int rp = vK[p] ? (wi / 132) : 0;
            int tp = (wi - rp * 132) * 2;
            ldsK[p] = rp * KRC_STRIDE + tp;
            taK[p] = vK[p] ? (tp - rp) : -1000;
        }
    }
    const float* Kfrow = Kc + (long)h * L;

    // B staging: one (b-row, 4-float) chunk per thread
    const int bb = tid >> 5;
    const int q8 = (tid & 31) * 4;
    const long ubase = ((long)bb * H + h) * L;

    f32x4 acc[4][4];
    {
        f32x4 z = {0.f, 0.f, 0.f, 0.f};
        #pragma unroll
        for (int a = 0; a < 4; ++a)
            #pragma unroll
            for (int b = 0; b < 4; ++b) acc[a][b] = z;
    }

    int sc4[4];
    #pragma unroll
    for (int nb = 0; nb < 4; ++nb) {
        int il = wn * 8 + nb * 2 + (m >> 3);
        sc4[nb] = (i0 + il) % SLOTS;
    }
    int slotw = (i0 >= 1) ? ((i0 - 1) % SLOTS) : (SLOTS - 1);

    // ---- prologue: stage 16 window tiles (f32 -> bf16); tier0 also Krc[0] ----
    #pragma unroll
    for (int batch = 0; batch < 2; ++batch) {
        uint2 a8[8];
        #pragma unroll
        for (int q = 0; q < 8; ++q) {
            int j = i0 + batch * 8 + q;
            float4 v = *(const float4*)(u + ubase + (long)j * TILE + q8);
            a8[q].x = f2bf(v.x) | ((unsigned)f2bf(v.y) << 16);
            a8[q].y = f2bf(v.z) | ((unsigned)f2bf(v.w) << 16);
        }
        #pragma unroll
        for (int q = 0; q < 8; ++q) {
            int j = i0 + batch * 8 + q;
            *(uint2*)(Bs + (j % SLOTS) * SLOT_STRIDE + bb * BROW + q8) = a8[q];
        }
    }
    if (UK == 0) {
        #pragma unroll
        for (int p = 0; p < 5; ++p) {
            if (vK[p]) {
                unsigned int s0 = 0, s1 = 0;
                int ta = taK[p];
                int ka = 127 - ta;
                if (ta >= 0 && ta < 256 && ka >= 0) s0 = f2bf(Kfrow[ka]);
                if (ta + 1 >= 0 && ta + 1 < 256 && (ka - 1) >= 0) s1 = f2bf(Kfrow[ka - 1]);
                *(unsigned int*)(Krc + ldsK[p]) = s0 | (s1 << 16);
            }
        }
    }
    bf16x8 af[10], afn[5] = {};
    if (UK) {
        #pragma unroll
        for (int o = 0; o < 5; ++o) af[o] = *(const bf16x8*)(pA + (o - 3) * 32);
    }
    __syncthreads();

    const bf16x8 z8 = {};

    // ---- main loop: one barrier per iter ----
    for (int d = 0; d <= dmax; ++d) {
        const int dn = d + 1;
        const int jn = i0 - 1 - d;

        // A frags: current-iter high half (UK1) or all from LDS (UK0)
        if (UK) {
            #pragma unroll
            for (int o = 5; o < 10; ++o) af[o] = *(const bf16x8*)(pA + (o - 3) * 32);
        } else {
            const char* Ab = (const char*)Krc + (d & 1) * (KRC_BUF * 2) + cAb;
            #pragma unroll
            for (int o = 0; o < 10; ++o) af[o] = *(const bf16x8*)(Ab + (o - 3) * 32);
        }

        // stage next B tile: ISSUE the f32 load now, pack AFTER compute
        float4 fv = {0.f, 0.f, 0.f, 0.f};
        if (jn >= 0)
            fv = *(const float4*)(u + ubase + (long)jn * TILE + q8);

        // A prefetch for next iter (no barrier dependency)
        if (UK) {
            if (d < dmax) {
                #pragma unroll
                for (int o = 0; o < 5; ++o) afn[o] = *(const bf16x8*)(pA - 256 + (o - 3) * 32);
            }
        }
        // tier0: K window values for next iter (guarded f32)
        unsigned int kv[5] = {0u, 0u, 0u, 0u, 0u};
        if (UK == 0 && dn <= dmax) {
            #pragma unroll
            for (int p = 0; p < 5; ++p) {
                unsigned int s0 = 0, s1 = 0;
                int ta = taK[p];
                if (vK[p]) {
                    int ka = dn * TILE + 127 - ta;
                    if (ta >= 0 && ta < 256 && ka >= 0) s0 = f2bf(Kfrow[ka]);
                    if (ta + 1 >= 0 && ta + 1 < 256 && (ka - 1) >= 0) s1 = f2bf(Kfrow[ka - 1]);
                }
                kv[p] = s0 | (s1 << 16);
            }
        }

        // ---- compute ----
        const int dlim = d - i0;
        const unsigned short* Bp[4];
        #pragma unroll
        for (int nb = 0; nb < 4; ++nb)
            Bp[nb] = Bs + sc4[nb] * SLOT_STRIDE + cB;

        __builtin_amdgcn_s_setprio(1);
        #pragma unroll
        for (int kc = 0; kc < 4; ++kc) {
            #pragma unroll
            for (int nb = 0; nb < 4; ++nb) {
                const int nbg = wn * 4 + nb;
                if (2 * nbg + 1 >= dlim) {
                    bf16x8 bfr = *(const bf16x8*)(Bp[nb] + kc * 32);
                    // boundary col mask: col<0 at 2nbg+1==dlim  <=>  m>>3==0
                    if (2 * nbg + 1 == dlim) bfr = tb0 ? z8 : bfr;
                    acc[0][nb] = __builtin_amdgcn_mfma_f32_16x16x32_bf16(af[3 + 2 * kc], bfr, acc[0][nb], 0, 0, 0);
                    acc[1][nb] = __builtin_amdgcn_mfma_f32_16x16x32_bf16(af[2 + 2 * kc], bfr, acc[1][nb], 0, 0, 0);
                    acc[2][nb] = __builtin_amdgcn_mfma_f32_16x16x32_bf16(af[1 + 2 * kc], bfr, acc[2][nb], 0, 0, 0);
                    acc[3][nb] = __builtin_amdgcn_mfma_f32_16x16x32_bf16(af[0 + 2 * kc], bfr, acc[3][nb], 0, 0, 0);
                }
            }
        }
        __builtin_amdgcn_s_setprio(0);

        // commit staged data for next iter (pack happens HERE, behind the MFMAs)
        if (UK == 0 && dn <= dmax) {
            unsigned short* Kw = Krc + (dn & 1) * KRC_BUF;
            #pragma unroll
            for (int p = 0; p < 5; ++p)
                if (vK[p]) *(unsigned int*)(Kw + ldsK[p]) = kv[p];
        }
        if (jn >= 0) {
            uint2 bv;
            bv.x = f2bf(fv.x) | ((unsigned)f2bf(fv.y) << 16);
            bv.y = f2bf(fv.z) | ((unsigned)f2bf(fv.w) << 16);
            *(uint2*)(Bs + slotw * SLOT_STRIDE + bb * BROW + q8) = bv;
        }

        slotw = slotw ? slotw - 1 : SLOTS - 1;
        #pragma unroll
        for (int nb = 0; nb < 4; ++nb)
            sc4[nb] = sc4[nb] ? sc4[nb] - 1 : SLOTS - 1;
        if (UK) {
            #pragma unroll
            for (int o = 0; o < 5; ++o) af[o] = afn[o];
            pA -= 256;
        }
        __syncthreads();
    }

    // ---- epilogue: LDS transpose (2 passes), skip-add, store ----
    const float Dh = Dp[h];
    const int ec = tid >> 2;
    const int ps = (tid & 3) * 32;
    #pragma unroll
    for (int pass = 0; pass < 2; ++pass) {
        if (wn == pass) {
            #pragma unroll
            for (int rb = 0; rb < 4; ++rb) {
                int p = wm * 64 + rb * 16 + quad * 4;  // C/D row = quad*4+reg
                #pragma unroll
                for (int nb = 0; nb < 4; ++nb) {
                    int cloc = nb * 16 + m;            // C/D col = lane&15
                    *(f32x4*)(Ep + cloc * EP_STRIDE + p) = acc[rb][nb];
                }
            }
        }
        __syncthreads();
        {
            int cg = pass * 64 + ec;
            int b  = cg & 7;
            int i  = i0 + (cg >> 3);
            long base = ((long)b * H + h) * L + (long)i * TILE + ps;
            const float* ep = Ep + ec * EP_STRIDE + ps;
            const float* us = u + base;
            if (cplx) {
                if (2 * (base + 32) <= out_floats) {
                    float4* o = (float4*)(outf + 2 * base);
                    #pragma unroll
                    for (int k4 = 0; k4 < 8; ++k4) {
                        float4 uv = ((const float4*)us)[k4];
                        float4 ev = *(const float4*)(ep + k4 * 4);
                        float4 o1, o2;
                        o1.x = ev.x + Dh * uv.x; o1.y = 0.f;
                        o1.z = ev.y + Dh * uv.y; o1.w = 0.f;
                        o2.x = ev.z + Dh * uv.z; o2.y = 0.f;
                        o2.z = ev.w + Dh * uv.w; o2.w = 0.f;
                        o[k4 * 2]     = o1;
                        o[k4 * 2 + 1] = o2;
                    }
                }
            } else {
                if (base + 32 <= out_floats) {
                    float4* o = (float4*)(outf + base);
                    #pragma unroll
                    for (int k4 = 0; k4 < 8; ++k4) {
                        float4 uv = ((const float4*)us)[k4];
                        float4 ev = *(const float4*)(ep + k4 * 4);
                        float4 ov;
                        ov.x = ev.x + Dh * uv.x;
                        ov.y = ev.y + Dh * uv.y;
                        ov.z = ev.z + Dh * uv.z;
                        ov.w = ev.w + Dh * uv.w;
                        o[k4] = ov;
                    }
                }
            }
        }
        __syncthreads();
    }
}

extern "C" void kernel_launch(void* const* d_in, const int* in_sizes, int n_in,
                              void* d_out, int out_size, void* d_ws, size_t ws_size,
                              hipStream_t stream) {
    const float* u  = (const float*)d_in[0];
    const float* Kc = (const float*)d_in[1];
    const float* Dp = (const float*)d_in[2];
    const int H = in_sizes[2];
    const int L = in_sizes[1] / H;          // 8192
    const int G = L / (TILE * IGRP);        // 4
    const int RS = L + 272;
    const int cplx = (out_size >= 2 * in_sizes[0]) ? 1 : 0;

    const size_t kr8_bytes = (size_t)H * 8 * RS * 2;
    const int tier = (ws_size >= kr8_bytes) ? 1 : 0;
    unsigned short* KR8 = (unsigned short*)d_ws;

    if (tier) {
        dim3 gk((RS / 4 + 255) / 256, 8, H);
        build_KR8<<<gk, 256, 0, stream>>>(Kc, KR8, L, RS);
        conv_main<1><<<H * G, 256, 0, stream>>>(u, Kc, Dp, KR8, (float*)d_out,
                                                H, L, G, RS, cplx, (long)out_size);
    } else {
        conv_main<0><<<H * G, 256, 0, stream>>>(u, Kc, Dp, KR8, (float*)d_out,
                                                H, L, G, RS, cplx, (long)out_size);
    }
}